// Round 1
// baseline (145.054 us; speedup 1.0000x reference)
//
#include <hip/hip_runtime.h>

// B=4096, S=512, D=2, H=4. One 16-lane group per batch element:
// lane = g*4 + j, quads g = gates in order [i, u, f, o], j = hidden index.
// All cross-lane exchanges via DPP (no LDS):
//   - within-quad (across j): explicit quad_perm (unambiguous)
//   - across quads (g^1): ROW_HALF_MIRROR + quad_perm[3,2,1,0]
//   - across quads (g^2): row_ror:8 (self-inverse, direction-free)

#define NS 512

static constexpr long SP_OFF  = 4194304;   // sampler_probs
static constexpr long EO_OFF  = 8388608;   // estimator_out
static constexpr long LO_OFF  = 10485760;  // lstm_out
static constexpr long FID_OFF = 18874368;  // fid_adj

template<int CTRL>
__device__ __forceinline__ float dppf(float v) {
    return __int_as_float(__builtin_amdgcn_mov_dpp(__float_as_int(v), CTRL, 0xF, 0xF, true));
}

// value from lane (quad^1, same j): half-mirror maps (q,j)->(q^1,3-j); quad_perm[3,2,1,0] fixes j
__device__ __forceinline__ float xor4f(float v) {
    float t = dppf<0x141>(v);   // ROW_HALF_MIRROR
    return dppf<0x1B>(t);       // quad_perm [3,2,1,0]
}

__device__ __forceinline__ float sigm(float x) {
    return __builtin_amdgcn_rcpf(1.0f + __expf(-x));
}

__global__ __launch_bounds__(64) void qlstm_kernel(
    const float* __restrict__ xin,
    const float* __restrict__ Wi, const float* __restrict__ bi,
    const float* __restrict__ Wu, const float* __restrict__ bu,
    const float* __restrict__ Wf, const float* __restrict__ bf,
    const float* __restrict__ Wo, const float* __restrict__ bo,
    const float* __restrict__ ti, const float* __restrict__ tu,
    const float* __restrict__ tf, const float* __restrict__ to_,
    const float* __restrict__ sw, const float* __restrict__ ew,
    float* __restrict__ out)
{
    const int tid = threadIdx.x;
    const int gl  = tid & 15;
    const int g   = gl >> 2;
    const int j   = gl & 3;
    const int b   = blockIdx.x * 4 + (tid >> 4);

    // gate order on quads: [i, u, f, o]
    const float* Wt; const float* bt; const float* tht;
    if      (g == 0) { Wt = Wi; bt = bi; tht = ti;  }
    else if (g == 1) { Wt = Wu; bt = bu; tht = tu;  }
    else if (g == 2) { Wt = Wf; bt = bf; tht = tf;  }
    else             { Wt = Wo; bt = bo; tht = to_; }

    // weights: x-part, then h-part permuted to match rotation order h_{j+m}
    const float w0  = Wt[j*6 + 0], w1 = Wt[j*6 + 1];
    const float wh0 = Wt[j*6 + 2 +  j];
    const float wh1 = Wt[j*6 + 2 + ((j+1)&3)];
    const float wh2 = Wt[j*6 + 2 + ((j+2)&3)];
    const float wh3 = Wt[j*6 + 2 + ((j+3)&3)];
    const float bth = bt[j] + tht[j];          // theta folded into bias (angles add)

    // sampler/estimator constants:
    // P0 = 1/2 + (cosTh*cos p0 - sinTh*sin p0*sin p1)/2 ; probs0 = sigmoid(2*P0-1)
    const float thsum = sw[0] + sw[1] + sw[2] + sw[3];
    const float K1 = __cosf(thsum), K2 = __sinf(thsum), Ke = __sinf(ew[0]);

    const bool isU = (g == 1);
    const bool jb0 = (j & 1), jb1 = (j & 2) != 0;
    const bool gb0 = (g & 1), gb1 = (g & 2) != 0;
    const bool gIs0 = (g == 0), gIs1 = (g == 1);

    // per-lane output stream: each lane writes one float per step
    // g0: [sl0, sl1, sp0, sp1][j]  stride 2
    // g1: estimator (4-way dup)    stride 1
    // g2/g3: lstm_out h_j (2-way dup) stride 4
    const long n0 = (long)b * NS;
    float* sptr;
    long sstride;
    if (g == 0) {
        sptr = out + ((j < 2) ? (2*n0 + j) : (SP_OFF + 2*n0 + (j - 2)));
        sstride = 2;
    } else if (g == 1) {
        sptr = out + EO_OFF + n0;
        sstride = 1;
    } else {
        sptr = out + LO_OFF + 4*n0 + j;
        sstride = 4;
    }

    const float4* xv = (const float4*)(xin + (long)b * (NS * 2)); // xv[k] = x for steps 2k,2k+1

    float h = 0.f, h1 = 0.f, h2 = 0.f, h3 = 0.f, cst = 0.f;
    float4 xa = xv[0];

    #pragma unroll 1
    for (int t2 = 0; t2 < NS/2; ++t2) {
        const float4 xb = xv[(t2 + 1) & (NS/2 - 1)];   // prefetch (clamped wrap, unused at end)

        #pragma unroll
        for (int sub = 0; sub < 2; ++sub) {
            const float X0 = sub ? xa.z : xa.x;
            const float X1 = sub ? xa.w : xa.y;

            // z = W.[x,h] + b + theta  (h-parts in rotation order)
            float z = __builtin_fmaf(X0, w0, bth);
            z = __builtin_fmaf(X1, w1, z);
            z = __builtin_fmaf(h,  wh0, z);
            z = __builtin_fmaf(h1, wh1, z);
            z = __builtin_fmaf(h2, wh2, z);
            z = __builtin_fmaf(h3, wh3, z);
            const float cc = __cosf(z);

            // qlayer within quad: out0=c1c2c3, out1=c0c1, out2=c0c1c2, out3=c0c1c2c3
            const float c1x  = dppf<0xB1>(cc);    // c_{j^1}
            const float pr   = cc * c1x;          // pair product {c0c1,c0c1,c2c3,c2c3}
            const float pr2  = dppf<0x4E>(pr);    // pairprod_{j^2}
            const float fullp = pr * pr2;
            const float v0   = c1x * pr2;         // c1*c2c3  (lane j=0)
            const float v2   = pr2 * cc;          // c0c1*c2  (lane j=2)
            const float q = jb1 ? (jb0 ? fullp : v2) : (jb0 ? pr : v0);

            // activation: sigmoid for i,f,o; tanh = 2*sigmoid(2x)-1 for u
            const float aarg = isU ? (q + q) : q;
            const float s    = sigm(aarg);
            const float act  = isU ? __builtin_fmaf(2.f, s, -1.f) : s;

            // gather gates across quads: x1v=act_{g^1}, y8=act_{g^2}, x1y=act_{g^3}
            const float x1v = xor4f(act);
            const float y8  = dppf<0x128>(act);   // row_ror:8
            const float x1y = xor4f(y8);
            const float pmA = act * x1v;          // i*u on g0,g1
            const float pmB = y8  * x1y;          // i*u on g2,g3
            const float iu  = gb1 ? pmB : pmA;
            const float fv  = gb1 ? (gb0 ? x1v : act) : (gb0 ? x1y : y8);  // f = [y8,x1y,act,x1v][g]
            const float ov  = gb1 ? (gb0 ? act : x1v) : (gb0 ? y8 : x1y);  // o = [x1y,y8,x1v,act][g]

            // cell/hidden update (replicated consistently across quads)
            cst = __builtin_fmaf(fv, cst, iu);
            const float tnh = __builtin_fmaf(2.f, sigm(cst + cst), -1.f);
            h = ov * tnh;
            h1 = dppf<0x39>(h);   // h_{j+1}
            h2 = dppf<0x4E>(h);   // h_{j+2}
            h3 = dppf<0x93>(h);   // h_{j+3}

            // sampler / estimator (closed form), on all lanes
            const float p0 = jb1 ? (jb0 ? h1 : h2) : (jb0 ? h3 : h);
            const float p1 = jb1 ? (jb0 ? h2 : h3) : (jb0 ? h : h1);
            const float s0 = __sinf(p0), c0v = __cosf(p0), s1 = __sinf(p1);
            const float t1 = K2 * s0;
            const float Dv = __builtin_fmaf(K1, c0v, -(t1 * s1)); // 2*P0-1
            const float P0 = __builtin_fmaf(0.5f, Dv, 0.5f);
            const float sp0 = sigm(Dv);                            // softmax prob 0
            const float sval = jb1 ? (jb0 ? (1.f - sp0) : sp0) : (jb0 ? (1.f - P0) : P0);
            const float val  = gIs0 ? sval : (gIs1 ? (Ke * s0) : h);

            *sptr = val;
            sptr += sstride;
        }
        xa = xb;
    }
}

__global__ __launch_bounds__(256) void fid_kernel(float* __restrict__ out) {
    const int idx = blockIdx.x * blockDim.x + threadIdx.x;
    const int r = idx >> 9, c = idx & 511;
    out[FID_OFF + idx] = (r == c) ? 0.f : 1.f;
}

extern "C" void kernel_launch(void* const* d_in, const int* in_sizes, int n_in,
                              void* d_out, int out_size, void* d_ws, size_t ws_size,
                              hipStream_t stream) {
    (void)in_sizes; (void)n_in; (void)d_ws; (void)ws_size; (void)out_size;
    const float* xin = (const float*)d_in[0];
    const float* Wf  = (const float*)d_in[1];  const float* bf = (const float*)d_in[2];
    const float* Wi  = (const float*)d_in[3];  const float* bi = (const float*)d_in[4];
    const float* Wu  = (const float*)d_in[5];  const float* bu = (const float*)d_in[6];
    const float* Wo  = (const float*)d_in[7];  const float* bo = (const float*)d_in[8];
    const float* tf  = (const float*)d_in[9];  const float* ti = (const float*)d_in[10];
    const float* tu  = (const float*)d_in[11]; const float* to_ = (const float*)d_in[12];
    const float* sw  = (const float*)d_in[13]; const float* ew = (const float*)d_in[14];
    float* out = (float*)d_out;

    hipLaunchKernelGGL(fid_kernel, dim3(262144/256), dim3(256), 0, stream, out);
    hipLaunchKernelGGL(qlstm_kernel, dim3(4096/4), dim3(64), 0, stream,
                       xin, Wi, bi, Wu, bu, Wf, bf, Wo, bo,
                       ti, tu, tf, to_, sw, ew, out);
}

// Round 2
// 138.671 us; speedup vs baseline: 1.0460x; 1.0460x over previous
//
#include <hip/hip_runtime.h>

// B=4096, S=512, D=2, H=4. One 16-lane group per batch element:
// lane = g*4 + j, quads g = gates in order [i, u, f, o], j = hidden index.
// Recurrence kernel writes ONLY lstm_out; sampler/estimator/softmax are a
// separate massively-parallel elementwise pass over lstm_out.
// Activations via Pade rationals (inputs provably bounded):
//   gate q in [-1,1]  (product of cosines);  |cst| <= s(1)/(1-s(1)) ~ 2.07
//   R5(x) = x(945+105x^2+x^4)/(945+420x^2+15x^4)            tanh, err<1e-6 on [-1,1]
//   R7(x) = x(10395+1260x^2+21x^4)/(10395+4725x^2+210x^4+x^6) tanh, err~1e-5 on [-2.1,2.1]
//   sigma(q) = 0.5 + 0.5*R5(q/2)

#define NS 512

static constexpr long SP_OFF  = 4194304;   // sampler_probs
static constexpr long EO_OFF  = 8388608;   // estimator_out
static constexpr long LO_OFF  = 10485760;  // lstm_out
static constexpr long FID_OFF = 18874368;  // fid_adj

template<int CTRL>
__device__ __forceinline__ float dppf(float v) {
    return __int_as_float(__builtin_amdgcn_mov_dpp(__float_as_int(v), CTRL, 0xF, 0xF, true));
}

// value from lane (quad^1, same j): half-mirror maps (q,j)->(q^1,3-j); quad_perm[3,2,1,0] fixes j
__device__ __forceinline__ float xor4f(float v) {
    float t = dppf<0x141>(v);   // ROW_HALF_MIRROR
    return dppf<0x1B>(t);       // quad_perm [3,2,1,0]
}

__global__ __launch_bounds__(64) void qlstm_kernel(
    const float* __restrict__ xin,
    const float* __restrict__ Wi, const float* __restrict__ bi,
    const float* __restrict__ Wu, const float* __restrict__ bu,
    const float* __restrict__ Wf, const float* __restrict__ bf,
    const float* __restrict__ Wo, const float* __restrict__ bo,
    const float* __restrict__ ti, const float* __restrict__ tu,
    const float* __restrict__ tf, const float* __restrict__ to_,
    float* __restrict__ out)
{
    const int tid = threadIdx.x;
    const int gl  = tid & 15;
    const int g   = gl >> 2;
    const int j   = gl & 3;
    const int b   = blockIdx.x * 4 + (tid >> 4);

    // gate order on quads: [i, u, f, o]
    const float* Wt; const float* bt; const float* tht;
    if      (g == 0) { Wt = Wi; bt = bi; tht = ti;  }
    else if (g == 1) { Wt = Wu; bt = bu; tht = tu;  }
    else if (g == 2) { Wt = Wf; bt = bf; tht = tf;  }
    else             { Wt = Wo; bt = bo; tht = to_; }

    // weights: x-part, then h-part permuted to match rotation order h_{j+m}
    const float w0  = Wt[j*6 + 0], w1 = Wt[j*6 + 1];
    const float wh0 = Wt[j*6 + 2 +  j];
    const float wh1 = Wt[j*6 + 2 + ((j+1)&3)];
    const float wh2 = Wt[j*6 + 2 + ((j+2)&3)];
    const float wh3 = Wt[j*6 + 2 + ((j+3)&3)];
    const float bth = bt[j] + tht[j];          // theta folded into bias (angles add)

    const bool isU = (g == 1);
    const bool jb0 = (j & 1), jb1 = (j & 2) != 0;
    const bool gb0 = (g & 1), gb1 = (g & 2) != 0;

    // per-lane activation constants: sigma(q)=0.5+0.5*R5(q/2); tanh(q)=R5(q)
    const float ysc = isU ? 1.0f : 0.5f;
    const float sA  = isU ? 1.0f : 0.5f;
    const float sB  = isU ? 0.0f : 0.5f;

    // all 16 lanes store h_j (4-way duplicated same-value addresses coalesce)
    const long n0 = (long)b * NS;
    float* sptr = out + LO_OFF + 4*n0 + j;

    const float4* xv = (const float4*)(xin + (long)b * (NS * 2)); // xv[k] = x for steps 2k,2k+1

    float h = 0.f, h1 = 0.f, h2 = 0.f, h3 = 0.f, cst = 0.f;
    float4 xa = xv[0];

    #pragma unroll 1
    for (int t2 = 0; t2 < NS/2; ++t2) {
        const float4 xb = xv[(t2 + 1) & (NS/2 - 1)];   // prefetch (clamped wrap, unused at end)

        #pragma unroll
        for (int sub = 0; sub < 2; ++sub) {
            const float X0 = sub ? xa.z : xa.x;
            const float X1 = sub ? xa.w : xa.y;

            // xz is off the h-critical-path; z-FMA tree depth 3 from h
            const float xz = __builtin_fmaf(X1, w1, __builtin_fmaf(X0, w0, bth));
            const float T01 = __builtin_fmaf(h1, wh1, __builtin_fmaf(h, wh0, xz));
            const float T23 = __builtin_fmaf(h3, wh3, h2 * wh2);
            const float z = T01 + T23;
            const float cc = __cosf(z);

            // qlayer within quad: out0=c1c2c3, out1=c0c1, out2=c0c1c2, out3=c0c1c2c3
            const float c1x  = dppf<0xB1>(cc);    // c_{j^1}
            const float pr   = cc * c1x;          // pair product {c0c1,c0c1,c2c3,c2c3}
            const float pr2  = dppf<0x4E>(pr);    // pairprod_{j^2}
            const float fullp = pr * pr2;
            const float v0   = c1x * pr2;         // c1*c2c3  (lane j=0)
            const float v2   = pr2 * cc;          // c0c1*c2  (lane j=2)
            const float q = jb1 ? (jb0 ? fullp : v2) : (jb0 ? pr : v0);

            // activation via R5 Pade (no exp): act = sA*R5(ysc*q) + sB
            const float y   = q * ysc;
            const float y2  = y * y;
            const float num = y * __builtin_fmaf(y2, y2 + 105.f, 945.f);
            const float den = __builtin_fmaf(y2, __builtin_fmaf(y2, 15.f, 420.f), 945.f);
            const float act = __builtin_fmaf(num * __builtin_amdgcn_rcpf(den), sA, sB);

            // gather gates across quads: x1v=act_{g^1}, y8=act_{g^2}, x1y=act_{g^3}
            const float x1v = xor4f(act);
            const float y8  = dppf<0x128>(act);   // row_ror:8
            const float x1y = xor4f(y8);
            const float pmA = act * x1v;          // i*u on g0,g1
            const float pmB = y8  * x1y;          // i*u on g2,g3
            const float iu  = gb1 ? pmB : pmA;
            const float fv  = gb1 ? (gb0 ? x1v : act) : (gb0 ? x1y : y8);  // f = [y8,x1y,act,x1v][g]
            const float ov  = gb1 ? (gb0 ? act : x1v) : (gb0 ? y8 : x1y);  // o = [x1y,y8,x1v,act][g]

            // cell/hidden update; tanh via R7 Pade (|cst| <= ~2.07)
            cst = __builtin_fmaf(fv, cst, iu);
            const float x2 = cst * cst;
            const float cn = cst * __builtin_fmaf(x2, __builtin_fmaf(x2, 21.f, 1260.f), 10395.f);
            const float cd = __builtin_fmaf(x2, __builtin_fmaf(x2, x2 + 210.f, 4725.f), 10395.f);
            const float tnh = cn * __builtin_amdgcn_rcpf(cd);
            h = ov * tnh;
            h1 = dppf<0x39>(h);   // h_{j+1}
            h2 = dppf<0x4E>(h);   // h_{j+2}
            h3 = dppf<0x93>(h);   // h_{j+3}

            *sptr = h;
            sptr += 4;
        }
        xa = xb;
    }
}

// Elementwise pass over lstm_out: sampler logits/probs + estimator.
// P0 = 1/2 + (cosTh*cos p0 - sinTh*sin p0*sin p1)/2 ; probs0 = sigmoid(2*P0-1)
__global__ __launch_bounds__(256) void epilogue_kernel(
    const float* __restrict__ sw, const float* __restrict__ ew,
    float* __restrict__ out)
{
    const long idx = (long)blockIdx.x * 256 + threadIdx.x;   // 0 .. B*S-1
    const float thsum = sw[0] + sw[1] + sw[2] + sw[3];
    const float K1 = __cosf(thsum), K2 = __sinf(thsum), Ke = __sinf(ew[0]);

    const float2 hp = *(const float2*)(out + LO_OFF + idx * 4); // h0, h1
    const float s0 = __sinf(hp.x), c0 = __cosf(hp.x), s1 = __sinf(hp.y);
    const float Dv = __builtin_fmaf(K1, c0, -(K2 * s0 * s1));   // 2*P0-1
    const float P0 = __builtin_fmaf(0.5f, Dv, 0.5f);
    const float sp0 = __builtin_amdgcn_rcpf(1.f + __expf(-Dv));

    float2 sl; sl.x = P0;  sl.y = 1.f - P0;
    float2 sp; sp.x = sp0; sp.y = 1.f - sp0;
    ((float2*)out)[idx] = sl;
    ((float2*)(out + SP_OFF))[idx] = sp;
    out[EO_OFF + idx] = Ke * s0;
}

__global__ __launch_bounds__(256) void fid_kernel(float* __restrict__ out) {
    const int idx = blockIdx.x * blockDim.x + threadIdx.x;
    const int r = idx >> 9, c = idx & 511;
    out[FID_OFF + idx] = (r == c) ? 0.f : 1.f;
}

extern "C" void kernel_launch(void* const* d_in, const int* in_sizes, int n_in,
                              void* d_out, int out_size, void* d_ws, size_t ws_size,
                              hipStream_t stream) {
    (void)in_sizes; (void)n_in; (void)d_ws; (void)ws_size; (void)out_size;
    const float* xin = (const float*)d_in[0];
    const float* Wf  = (const float*)d_in[1];  const float* bf = (const float*)d_in[2];
    const float* Wi  = (const float*)d_in[3];  const float* bi = (const float*)d_in[4];
    const float* Wu  = (const float*)d_in[5];  const float* bu = (const float*)d_in[6];
    const float* Wo  = (const float*)d_in[7];  const float* bo = (const float*)d_in[8];
    const float* tf  = (const float*)d_in[9];  const float* ti = (const float*)d_in[10];
    const float* tu  = (const float*)d_in[11]; const float* to_ = (const float*)d_in[12];
    const float* sw  = (const float*)d_in[13]; const float* ew = (const float*)d_in[14];
    float* out = (float*)d_out;

    hipLaunchKernelGGL(fid_kernel, dim3(262144/256), dim3(256), 0, stream, out);
    hipLaunchKernelGGL(qlstm_kernel, dim3(4096/4), dim3(64), 0, stream,
                       xin, Wi, bi, Wu, bu, Wf, bf, Wo, bo,
                       ti, tu, tf, to_, out);
    hipLaunchKernelGGL(epilogue_kernel, dim3(2097152/256), dim3(256), 0, stream, sw, ew, out);
}

// Round 3
// 118.218 us; speedup vs baseline: 1.2270x; 1.1730x over previous
//
#include <hip/hip_runtime.h>

// B=4096, S=512, D=2, H=4. One 16-lane group per batch element:
// lane = g*4 + j, quads g = gates in order [i, u, f, o], j = hidden index.
// 16-step phases: 8 float4 x-loads per phase (prefetch 1 phase ahead, issued
// before stores), 4 coalesced h-stores per phase (1 dword/lane per 4 steps,
// delayed a full phase). Gate activation = odd deg-7 poly (no rcp); cell tanh
// = R7 Pade with rcp overlapped by ov*cn.

#define NS 512

static constexpr long SP_OFF  = 4194304;   // sampler_probs
static constexpr long EO_OFF  = 8388608;   // estimator_out
static constexpr long LO_OFF  = 10485760;  // lstm_out
static constexpr long FID_OFF = 18874368;  // fid_adj

template<int CTRL>
__device__ __forceinline__ float dppf(float v) {
    return __int_as_float(__builtin_amdgcn_mov_dpp(__float_as_int(v), CTRL, 0xF, 0xF, true));
}

// value from lane (quad^1, same j): half-mirror maps (q,j)->(q^1,3-j); quad_perm[3,2,1,0] fixes j
__device__ __forceinline__ float xor4f(float v) {
    float t = dppf<0x141>(v);   // ROW_HALF_MIRROR
    return dppf<0x1B>(t);       // quad_perm [3,2,1,0]
}

// one LSTM step; X0,X1 = inputs, GSEL = (g == step&3) hoisted bool, HK = staging reg
#define STEP(X0, X1, GSEL, HK)                                                   \
    {                                                                            \
        const float xz  = __builtin_fmaf(X1, w1, __builtin_fmaf(X0, w0, bth));   \
        const float T01 = __builtin_fmaf(h1, wh1, __builtin_fmaf(h, wh0, xz));   \
        const float T23 = __builtin_fmaf(h3, wh3, h2 * wh2);                     \
        const float z   = T01 + T23;                                             \
        const float cc  = __cosf(z);                                             \
        const float c1x = dppf<0xB1>(cc);                                        \
        const float pr  = cc * c1x;                                              \
        const float pr2 = dppf<0x4E>(pr);                                        \
        const float fullp = pr * pr2;                                            \
        const float v0  = c1x * pr2;                                             \
        const float v2  = pr2 * cc;                                              \
        const float q   = jb1 ? (jb0 ? fullp : v2) : (jb0 ? pr : v0);            \
        const float y   = q * ysc;                                               \
        const float y2  = y * y;                                                 \
        const float P   = __builtin_fmaf(y2, __builtin_fmaf(y2,                  \
                            __builtin_fmaf(y2, C7, C5), C3), 1.0f);              \
        const float act = __builtin_fmaf(y * P, sA, sB);                         \
        const float x1v = xor4f(act);                                            \
        const float y8  = dppf<0x128>(act);                                      \
        const float x1y = dppf<0x128>(x1v);                                      \
        const float pmA = act * x1v;                                             \
        const float pmB = y8  * x1y;                                             \
        const float iu  = gb1 ? pmB : pmA;                                       \
        const float fv  = gb1 ? (gb0 ? x1v : act) : (gb0 ? x1y : y8);            \
        const float ov  = gb1 ? (gb0 ? act : x1v) : (gb0 ? y8 : x1y);            \
        cst = __builtin_fmaf(fv, cst, iu);                                       \
        const float x2c = cst * cst;                                             \
        const float cn  = cst * __builtin_fmaf(x2c,                              \
                            __builtin_fmaf(x2c, 21.f, 1260.f), 10395.f);         \
        const float cd  = __builtin_fmaf(x2c,                                    \
                            __builtin_fmaf(x2c, x2c + 210.f, 4725.f), 10395.f);  \
        h = (ov * cn) * __builtin_amdgcn_rcpf(cd);                               \
        h1 = dppf<0x39>(h);                                                      \
        h2 = dppf<0x4E>(h);                                                      \
        h3 = dppf<0x93>(h);                                                      \
        HK = (GSEL) ? h : HK;                                                    \
    }

// 4 steps from two float4s (steps: FA.xy, FA.zw, FB.xy, FB.zw)
#define STEP4(FA, FB, HK)          \
    STEP(FA.x, FA.y, gs0, HK)      \
    STEP(FA.z, FA.w, gs1, HK)      \
    STEP(FB.x, FB.y, gs2, HK)      \
    STEP(FB.z, FB.w, gs3, HK)

#define PHASE16(P0,P1,P2,P3,P4,P5,P6,P7)  \
    STEP4(P0, P1, hk0)                    \
    STEP4(P2, P3, hk1)                    \
    STEP4(P4, P5, hk2)                    \
    STEP4(P6, P7, hk3)

#define LOAD8(P0,P1,P2,P3,P4,P5,P6,P7, IDX)                         \
    P0 = xv[(IDX)+0]; P1 = xv[(IDX)+1]; P2 = xv[(IDX)+2];           \
    P3 = xv[(IDX)+3]; P4 = xv[(IDX)+4]; P5 = xv[(IDX)+5];           \
    P6 = xv[(IDX)+6]; P7 = xv[(IDX)+7];

#define STORE4()                                                    \
    spp[0] = hk0; spp[16] = hk1; spp[32] = hk2; spp[48] = hk3;      \
    spp += 64;

__global__ __launch_bounds__(64) void qlstm_kernel(
    const float* __restrict__ xin,
    const float* __restrict__ Wi, const float* __restrict__ bi,
    const float* __restrict__ Wu, const float* __restrict__ bu,
    const float* __restrict__ Wf, const float* __restrict__ bf,
    const float* __restrict__ Wo, const float* __restrict__ bo,
    const float* __restrict__ ti, const float* __restrict__ tu,
    const float* __restrict__ tf, const float* __restrict__ to_,
    float* __restrict__ out)
{
    const int tid = threadIdx.x;
    const int gl  = tid & 15;
    const int g   = gl >> 2;
    const int j   = gl & 3;
    const int b   = blockIdx.x * 4 + (tid >> 4);

    // gate order on quads: [i, u, f, o]
    const float* Wt; const float* bt; const float* tht;
    if      (g == 0) { Wt = Wi; bt = bi; tht = ti;  }
    else if (g == 1) { Wt = Wu; bt = bu; tht = tu;  }
    else if (g == 2) { Wt = Wf; bt = bf; tht = tf;  }
    else             { Wt = Wo; bt = bo; tht = to_; }

    // weights: x-part, then h-part permuted to match rotation order h_{j+m}
    const float w0  = Wt[j*6 + 0], w1 = Wt[j*6 + 1];
    const float wh0 = Wt[j*6 + 2 +  j];
    const float wh1 = Wt[j*6 + 2 + ((j+1)&3)];
    const float wh2 = Wt[j*6 + 2 + ((j+2)&3)];
    const float wh3 = Wt[j*6 + 2 + ((j+3)&3)];
    const float bth = bt[j] + tht[j];          // theta folded into bias (angles add)

    const bool isU = (g == 1);
    const bool jb0 = (j & 1), jb1 = (j & 2) != 0;
    const bool gb0 = (g & 1), gb1 = (g & 2) != 0;
    const bool gs0 = (g == 0), gs1 = (g == 1), gs2 = (g == 2), gs3 = (g == 3);

    // activation: sigma(q)=0.5+0.5*T(q/2); tanh(q)=T(q); T = odd deg-7 poly
    const float ysc = isU ? 1.0f : 0.5f;
    const float sA  = isU ? 1.0f : 0.5f;
    const float sB  = isU ? 0.0f : 0.5f;
    const float C3 = -0.33333333f, C5 = 0.123842f, C7 = -0.028914f;

    const long n0 = (long)b * NS;
    float* spp = out + LO_OFF + 4*n0 + gl;     // one dword per lane per 4 steps

    const float4* xv = (const float4*)(xin + (long)b * (NS * 2));

    float h = 0.f, h1 = 0.f, h2 = 0.f, h3 = 0.f, cst = 0.f;
    float hk0 = 0.f, hk1 = 0.f, hk2 = 0.f, hk3 = 0.f;

    float4 a0,a1,a2,a3,a4,a5,a6,a7;
    float4 b0,b1,b2,b3,b4,b5,b6,b7;
    LOAD8(a0,a1,a2,a3,a4,a5,a6,a7, 0)          // phase 0 (steps 0..15)

    #pragma unroll 1
    for (int m = 0; m < 16; ++m) {
        // ---- phase A (global phase p=2m): compute from bank a, load bank b ----
        if (m != 0) { STORE4() }               // store phase 2m-1's h
        LOAD8(b0,b1,b2,b3,b4,b5,b6,b7, (2*m+1)*8)
        PHASE16(a0,a1,a2,a3,a4,a5,a6,a7)
        // ---- phase B (p=2m+1): compute from bank b, load bank a ----
        STORE4()                               // store phase 2m's h
        LOAD8(a0,a1,a2,a3,a4,a5,a6,a7, ((2*m+2)*8) & 255)   // wraps harmlessly at m=15
        PHASE16(b0,b1,b2,b3,b4,b5,b6,b7)
    }
    STORE4()                                   // phase 31's h

}

// Elementwise pass over lstm_out: sampler logits/probs + estimator.
// P0 = 1/2 + (cosTh*cos p0 - sinTh*sin p0*sin p1)/2 ; probs0 = sigmoid(2*P0-1)
__global__ __launch_bounds__(256) void epilogue_kernel(
    const float* __restrict__ sw, const float* __restrict__ ew,
    float* __restrict__ out)
{
    const long idx = (long)blockIdx.x * 256 + threadIdx.x;   // 0 .. B*S-1
    const float thsum = sw[0] + sw[1] + sw[2] + sw[3];
    const float K1 = __cosf(thsum), K2 = __sinf(thsum), Ke = __sinf(ew[0]);

    const float2 hp = *(const float2*)(out + LO_OFF + idx * 4); // h0, h1
    const float s0 = __sinf(hp.x), c0 = __cosf(hp.x), s1 = __sinf(hp.y);
    const float Dv = __builtin_fmaf(K1, c0, -(K2 * s0 * s1));   // 2*P0-1
    const float P0 = __builtin_fmaf(0.5f, Dv, 0.5f);
    const float sp0 = __builtin_amdgcn_rcpf(1.f + __expf(-Dv));

    float2 sl; sl.x = P0;  sl.y = 1.f - P0;
    float2 sp; sp.x = sp0; sp.y = 1.f - sp0;
    ((float2*)out)[idx] = sl;
    ((float2*)(out + SP_OFF))[idx] = sp;
    out[EO_OFF + idx] = Ke * s0;
}

__global__ __launch_bounds__(256) void fid_kernel(float* __restrict__ out) {
    const int idx = blockIdx.x * blockDim.x + threadIdx.x;
    const int r = idx >> 9, c = idx & 511;
    out[FID_OFF + idx] = (r == c) ? 0.f : 1.f;
}

extern "C" void kernel_launch(void* const* d_in, const int* in_sizes, int n_in,
                              void* d_out, int out_size, void* d_ws, size_t ws_size,
                              hipStream_t stream) {
    (void)in_sizes; (void)n_in; (void)d_ws; (void)ws_size; (void)out_size;
    const float* xin = (const float*)d_in[0];
    const float* Wf  = (const float*)d_in[1];  const float* bf = (const float*)d_in[2];
    const float* Wi  = (const float*)d_in[3];  const float* bi = (const float*)d_in[4];
    const float* Wu  = (const float*)d_in[5];  const float* bu = (const float*)d_in[6];
    const float* Wo  = (const float*)d_in[7];  const float* bo = (const float*)d_in[8];
    const float* tf  = (const float*)d_in[9];  const float* ti = (const float*)d_in[10];
    const float* tu  = (const float*)d_in[11]; const float* to_ = (const float*)d_in[12];
    const float* sw  = (const float*)d_in[13]; const float* ew = (const float*)d_in[14];
    float* out = (float*)d_out;

    hipLaunchKernelGGL(fid_kernel, dim3(262144/256), dim3(256), 0, stream, out);
    hipLaunchKernelGGL(qlstm_kernel, dim3(4096/4), dim3(64), 0, stream,
                       xin, Wi, bi, Wu, bu, Wf, bf, Wo, bo,
                       ti, tu, tf, to_, out);
    hipLaunchKernelGGL(epilogue_kernel, dim3(2097152/256), dim3(256), 0, stream, sw, ew, out);
}

// Round 4
// 100.764 us; speedup vs baseline: 1.4395x; 1.1732x over previous
//
#include <hip/hip_runtime.h>

// B=4096, S=512, D=2, H=4. One 16-lane group per batch element:
// lane = g*4 + j, quads g = gates in order [i, u, f, o], j = hidden index.
// Recurrence kernel writes ONLY lstm_out; sampler/estimator/softmax+fid are a
// separate massively-parallel elementwise pass.
// Chain-optimized step: prescaled-weight v_cos, 2-level DPP cumprod with
// overlapped select, Estrin deg-7 activation (per-lane folded coeffs),
// bank-masked update_dpp gate gather, R5 Pade cell tanh.

#define NS 512

static constexpr long SP_OFF  = 4194304;   // sampler_probs
static constexpr long EO_OFF  = 8388608;   // estimator_out
static constexpr long LO_OFF  = 10485760;  // lstm_out
static constexpr long FID_OFF = 18874368;  // fid_adj

template<int CTRL>
__device__ __forceinline__ float dppf(float v) {
    return __int_as_float(__builtin_amdgcn_mov_dpp(__float_as_int(v), CTRL, 0xF, 0xF, true));
}

// merge: lanes in banks of BANK_MASK receive src permuted by CTRL; others keep old
template<int CTRL, int BANK_MASK>
__device__ __forceinline__ float dpp_merge(float old, float src) {
    return __int_as_float(__builtin_amdgcn_update_dpp(
        __float_as_int(old), __float_as_int(src), CTRL, 0xF, BANK_MASK, false));
}

// value from lane (quad^1, same j): half-mirror maps (q,j)->(q^1,3-j); quad_perm[3,2,1,0] fixes j
__device__ __forceinline__ float xor4f(float v) {
    float t = dppf<0x141>(v);   // ROW_HALF_MIRROR
    return dppf<0x1B>(t);       // quad_perm [3,2,1,0]
}

// one LSTM step; X0,X1 = inputs, K = step&3 (compile-time), HK = staging reg
#define STEP(X0, X1, K, HK)                                                      \
    {                                                                            \
        const float xz  = __builtin_fmaf(X1, w1, __builtin_fmaf(X0, w0, bth));   \
        const float f1  = __builtin_fmaf(h,  wh0, xz);                           \
        const float T01 = __builtin_fmaf(h1, wh1, f1);                           \
        const float T23 = __builtin_fmaf(h3, wh3, h2 * wh2);                     \
        const float z   = T01 + T23;            /* in revolutions */             \
        const float cc  = __builtin_amdgcn_cosf(z);                              \
        const float c1x = dppf<0xB1>(cc);       /* c_{j^1} */                    \
        const float pr  = cc * c1x;             /* pair product */               \
        const float pr2 = dppf<0x4E>(pr);       /* other pair's product */       \
        const float LHS = jb0 ? pr : (jb1 ? cc : c1x);  /* [c1x,pr,cc,pr] */     \
        const float LHSy = LHS * ysc;                                            \
        const float RHS = isj1 ? 1.0f : pr2;    /* [pr2,1,pr2,pr2] */            \
        const float y   = LHSy * RHS;                                            \
        const float y2  = y * y;                                                 \
        const float y4  = y2 * y2;                                               \
        const float pa  = __builtin_fmaf(y2, A3, A0);                            \
        const float pb  = __builtin_fmaf(y2, A7, A5);                            \
        const float P   = __builtin_fmaf(y4, pb, pa);                            \
        const float act = __builtin_fmaf(y, P, sB);                              \
        const float x1v = xor4f(act);           /* act@(g^1) */                  \
        const float pmA = act * x1v;            /* i*u on q0,1; f*o on q2,3 */   \
        const float W   = gb0 ? x1v : act;                                       \
        const float V   = gb0 ? act : x1v;                                       \
        const float iu  = dpp_merge<0x128, 0xC>(pmA, pmA); /* q2,3 <- ror8 */    \
        const float fv  = dpp_merge<0x128, 0x3>(W, W);     /* all = act@q2 */    \
        const float ov  = dpp_merge<0x128, 0x3>(V, V);     /* all = act@q3 */    \
        cst = __builtin_fmaf(fv, cst, iu);                                       \
        const float u   = cst * cst;                                             \
        const float oc  = ov * cst;                                              \
        const float Nn  = __builtin_fmaf(u, u + 105.f, 945.f);                   \
        const float Dd  = __builtin_fmaf(u, __builtin_fmaf(u, 15.f, 420.f), 945.f);\
        const float M   = oc * Nn;                                               \
        h = M * __builtin_amdgcn_rcpf(Dd);                                       \
        h1 = dppf<0x39>(h);                                                      \
        h2 = dppf<0x4E>(h);                                                      \
        h3 = dppf<0x93>(h);                                                      \
        HK = dpp_merge<0xE4, (1 << (K))>(HK, h);  /* bank K keeps its h */       \
    }

// 4 steps from two float4s (steps: FA.xy, FA.zw, FB.xy, FB.zw)
#define STEP4(FA, FB, HK)        \
    STEP(FA.x, FA.y, 0, HK)      \
    STEP(FA.z, FA.w, 1, HK)      \
    STEP(FB.x, FB.y, 2, HK)      \
    STEP(FB.z, FB.w, 3, HK)

#define PHASE16(P0,P1,P2,P3,P4,P5,P6,P7)  \
    STEP4(P0, P1, hk0)                    \
    STEP4(P2, P3, hk1)                    \
    STEP4(P4, P5, hk2)                    \
    STEP4(P6, P7, hk3)

#define LOAD8(P0,P1,P2,P3,P4,P5,P6,P7, IDX)                         \
    P0 = xv[(IDX)+0]; P1 = xv[(IDX)+1]; P2 = xv[(IDX)+2];           \
    P3 = xv[(IDX)+3]; P4 = xv[(IDX)+4]; P5 = xv[(IDX)+5];           \
    P6 = xv[(IDX)+6]; P7 = xv[(IDX)+7];

#define STORE4()                                                    \
    spp[0] = hk0; spp[16] = hk1; spp[32] = hk2; spp[48] = hk3;      \
    spp += 64;

__global__ __launch_bounds__(64) void qlstm_kernel(
    const float* __restrict__ xin,
    const float* __restrict__ Wi, const float* __restrict__ bi,
    const float* __restrict__ Wu, const float* __restrict__ bu,
    const float* __restrict__ Wf, const float* __restrict__ bf,
    const float* __restrict__ Wo, const float* __restrict__ bo,
    const float* __restrict__ ti, const float* __restrict__ tu,
    const float* __restrict__ tf, const float* __restrict__ to_,
    float* __restrict__ out)
{
    const int tid = threadIdx.x;
    const int gl  = tid & 15;
    const int g   = gl >> 2;
    const int j   = gl & 3;
    const int b   = blockIdx.x * 4 + (tid >> 4);

    // gate order on quads: [i, u, f, o]
    const float* Wt; const float* bt; const float* tht;
    if      (g == 0) { Wt = Wi; bt = bi; tht = ti;  }
    else if (g == 1) { Wt = Wu; bt = bu; tht = tu;  }
    else if (g == 2) { Wt = Wf; bt = bf; tht = tf;  }
    else             { Wt = Wo; bt = bo; tht = to_; }

    // weights prescaled by 1/(2*pi) so v_cos takes revolutions directly;
    // x-part, then h-part permuted to match rotation order h_{j+m}
    const float I2P = 0.15915494309189535f;
    const float w0  = Wt[j*6 + 0] * I2P, w1 = Wt[j*6 + 1] * I2P;
    const float wh0 = Wt[j*6 + 2 +  j]        * I2P;
    const float wh1 = Wt[j*6 + 2 + ((j+1)&3)] * I2P;
    const float wh2 = Wt[j*6 + 2 + ((j+2)&3)] * I2P;
    const float wh3 = Wt[j*6 + 2 + ((j+3)&3)] * I2P;
    const float bth = (bt[j] + tht[j]) * I2P;  // theta folded into bias (angles add)

    const bool isU = (g == 1);
    const bool jb0 = (j & 1), jb1 = (j & 2) != 0;
    const bool gb0 = (g & 1);
    const bool isj1 = (j == 1);

    // activation: sigma(q)=0.5+0.5*T(q/2); tanh(q)=T(q); T = odd deg-7 poly
    // per-lane folded coeffs: act = fma(y, A0+A3 y2+A5 y4+A7 y6, sB)
    const float ysc = isU ? 1.0f : 0.5f;
    const float sAv = isU ? 1.0f : 0.5f;
    const float sB  = isU ? 0.0f : 0.5f;
    const float A0 = sAv, A3 = sAv * -0.33333333f,
                A5 = sAv * 0.123842f, A7 = sAv * -0.028914f;

    const long n0 = (long)b * NS;
    float* spp = out + LO_OFF + 4*n0 + gl;     // one dword per lane per 4 steps

    const float4* xv = (const float4*)(xin + (long)b * (NS * 2));

    float h = 0.f, h1 = 0.f, h2 = 0.f, h3 = 0.f, cst = 0.f;
    float hk0 = 0.f, hk1 = 0.f, hk2 = 0.f, hk3 = 0.f;

    float4 a0,a1,a2,a3,a4,a5,a6,a7;
    float4 b0,b1,b2,b3,b4,b5,b6,b7;
    LOAD8(a0,a1,a2,a3,a4,a5,a6,a7, 0)          // phase 0 (steps 0..15)

    #pragma unroll 1
    for (int m = 0; m < 16; ++m) {
        // ---- phase 2m: load next bank, compute bank a, store ----
        LOAD8(b0,b1,b2,b3,b4,b5,b6,b7, (2*m+1)*8)
        PHASE16(a0,a1,a2,a3,a4,a5,a6,a7)
        STORE4()
        // ---- phase 2m+1: load next bank, compute bank b, store ----
        LOAD8(a0,a1,a2,a3,a4,a5,a6,a7, ((2*m+2)*8) & 255)   // wraps harmlessly at m=15
        PHASE16(b0,b1,b2,b3,b4,b5,b6,b7)
        STORE4()
    }
}

// Elementwise pass over lstm_out: sampler logits/probs + estimator (+ fid).
// P0 = 1/2 + (cosTh*cos p0 - sinTh*sin p0*sin p1)/2 ; probs0 = sigmoid(2*P0-1)
__global__ __launch_bounds__(256) void epilogue_kernel(
    const float* __restrict__ sw, const float* __restrict__ ew,
    float* __restrict__ out)
{
    const long idx = (long)blockIdx.x * 256 + threadIdx.x;   // 0 .. B*S-1
    const float thsum = sw[0] + sw[1] + sw[2] + sw[3];
    const float K1 = __cosf(thsum), K2 = __sinf(thsum), Ke = __sinf(ew[0]);

    const float2 hp = *(const float2*)(out + LO_OFF + idx * 4); // h0, h1
    const float s0 = __sinf(hp.x), c0 = __cosf(hp.x), s1 = __sinf(hp.y);
    const float Dv = __builtin_fmaf(K1, c0, -(K2 * s0 * s1));   // 2*P0-1
    const float P0 = __builtin_fmaf(0.5f, Dv, 0.5f);
    const float sp0 = __builtin_amdgcn_rcpf(1.f + __expf(-Dv));

    float2 sl; sl.x = P0;  sl.y = 1.f - P0;
    float2 sp; sp.x = sp0; sp.y = 1.f - sp0;
    ((float2*)out)[idx] = sl;
    ((float2*)(out + SP_OFF))[idx] = sp;
    out[EO_OFF + idx] = Ke * s0;

    if (idx < 262144) {   // fid_adj: 512x512 complete graph minus diagonal
        const int r = (int)idx >> 9, c = (int)idx & 511;
        out[FID_OFF + idx] = (r == c) ? 0.f : 1.f;
    }
}

extern "C" void kernel_launch(void* const* d_in, const int* in_sizes, int n_in,
                              void* d_out, int out_size, void* d_ws, size_t ws_size,
                              hipStream_t stream) {
    (void)in_sizes; (void)n_in; (void)d_ws; (void)ws_size; (void)out_size;
    const float* xin = (const float*)d_in[0];
    const float* Wf  = (const float*)d_in[1];  const float* bf = (const float*)d_in[2];
    const float* Wi  = (const float*)d_in[3];  const float* bi = (const float*)d_in[4];
    const float* Wu  = (const float*)d_in[5];  const float* bu = (const float*)d_in[6];
    const float* Wo  = (const float*)d_in[7];  const float* bo = (const float*)d_in[8];
    const float* tf  = (const float*)d_in[9];  const float* ti = (const float*)d_in[10];
    const float* tu  = (const float*)d_in[11]; const float* to_ = (const float*)d_in[12];
    const float* sw  = (const float*)d_in[13]; const float* ew = (const float*)d_in[14];
    float* out = (float*)d_out;

    hipLaunchKernelGGL(qlstm_kernel, dim3(4096/4), dim3(64), 0, stream,
                       xin, Wi, bi, Wu, bu, Wf, bf, Wo, bo,
                       ti, tu, tf, to_, out);
    hipLaunchKernelGGL(epilogue_kernel, dim3(2097152/256), dim3(256), 0, stream, sw, ew, out);
}